// Round 9
// baseline (2154.050 us; speedup 1.0000x reference)
//
#include <hip/hip_runtime.h>
#include <hip/hip_bf16.h>
#include <stdint.h>

// Problem dims
#define BB    16
#define CDD   5
#define HIS   100
#define SS    30
#define EE    256
#define HH    16
#define VV    16
#define QD    200
#define KK    3
#define TT    61     // 2*S+1
#define NCAND 80     // B*CDD
#define NITEM 1680   // NCAND + B*HIS
#define NFUS  240    // B*CDD*K

typedef __attribute__((ext_vector_type(8))) short bf16x8;
typedef __attribute__((ext_vector_type(4))) float f32x4;
#define MFMA16(a, b, c) __builtin_amdgcn_mfma_f32_16x16x32_bf16(a, b, c, 0, 0, 0)

// kfus swizzle (u32/float element index; 16B chunk c in [0,64))
__device__ __forceinline__ int SWZ(int l, int c) { return l * 256 + (((c) ^ (l & 7)) << 2); }
// kword swizzle: adds (l&24)>>1 so rows differing by 8 map to different bank quads
__device__ __forceinline__ int SWZW(int l, int c) {
    return l * 256 + (((c ^ (l & 7) ^ ((l & 24) >> 1))) << 2);
}

__device__ __forceinline__ float dot4(float4 a, float4 b) {
    return a.x * b.x + a.y * b.y + a.z * b.z + a.w * b.w;
}
__device__ __forceinline__ uint32_t f2bf(float x) {   // RNE f32->bf16 bits
    uint32_t u = __float_as_uint(x);
    return (u + 0x7fffu + ((u >> 16) & 1u)) >> 16;
}
// split x into bf16 hi/lo, packed (hi<<16)|lo
__device__ __forceinline__ uint32_t splitpack(float x) {
    uint32_t hb = f2bf(x);
    float hf = __uint_as_float(hb << 16);
    uint32_t lb = f2bf(x - hf);
    return (hb << 16) | lb;
}
union b8u4 { uint4 u; bf16x8 b; };
__device__ __forceinline__ bf16x8 hi8(uint4 a, uint4 b) {  // 8 packed u32 -> hi bf16x8
    b8u4 cv;
    cv.u.x = (a.x >> 16) | (a.y & 0xffff0000u);
    cv.u.y = (a.z >> 16) | (a.w & 0xffff0000u);
    cv.u.z = (b.x >> 16) | (b.y & 0xffff0000u);
    cv.u.w = (b.z >> 16) | (b.w & 0xffff0000u);
    return cv.b;
}
__device__ __forceinline__ bf16x8 lo8(uint4 a, uint4 b) {
    b8u4 cv;
    cv.u.x = (a.x & 0xffffu) | (a.y << 16);
    cv.u.y = (a.z & 0xffffu) | (a.w << 16);
    cv.u.z = (b.x & 0xffffu) | (b.y << 16);
    cv.u.w = (b.z & 0xffffu) | (b.w << 16);
    return cv.b;
}

// ---------------- Threefry2x32 (exact JAX reproduction) ----------------
__device__ __forceinline__ uint32_t rotl32(uint32_t v, int r) {
    return (v << r) | (v >> (32 - r));
}
__device__ __forceinline__ void tf2x32(uint32_t k0, uint32_t k1, uint32_t& x0, uint32_t& x1) {
    uint32_t k2 = k0 ^ k1 ^ 0x1BD11BDAu;
    x0 += k0; x1 += k1;
    const int r0[4] = {13, 15, 26, 6}, r1[4] = {17, 29, 16, 24};
    #pragma unroll
    for (int i = 0; i < 4; ++i) { x0 += x1; x1 = rotl32(x1, r0[i]); x1 ^= x0; }
    x0 += k1; x1 += k2 + 1u;
    #pragma unroll
    for (int i = 0; i < 4; ++i) { x0 += x1; x1 = rotl32(x1, r1[i]); x1 ^= x0; }
    x0 += k2; x1 += k0 + 2u;
    #pragma unroll
    for (int i = 0; i < 4; ++i) { x0 += x1; x1 = rotl32(x1, r0[i]); x1 ^= x0; }
    x0 += k0; x1 += k1 + 3u;
    #pragma unroll
    for (int i = 0; i < 4; ++i) { x0 += x1; x1 = rotl32(x1, r1[i]); x1 ^= x0; }
    x0 += k1; x1 += k2 + 4u;
    #pragma unroll
    for (int i = 0; i < 4; ++i) { x0 += x1; x1 = rotl32(x1, r0[i]); x1 ^= x0; }
    x0 += k2; x1 += k0 + 5u;
}

// ---------------- ktrans: Wk [256][200] -> WkT [200][256] ----------------
__global__ __launch_bounds__(256) void ktrans(const float* __restrict__ Wk,
                                              float* __restrict__ WkT) {
    int j = blockIdx.x;
    int r = threadIdx.x;
    WkT[j * 256 + r] = Wk[r * QD + j];
}

// ---------------- kprep: Wq [16][256][256] fp32 -> fragment-ordered bf16 hi/lo ----
// WF[((h*8+kt)*16+nt)*64+lane][0..7]=hi, [8..15]=lo; elem i <-> W[h][32kt+8g+i][16nt+ml]
__global__ __launch_bounds__(256) void kprep(const float* __restrict__ W,
                                             uint16_t* __restrict__ WF) {
    const int hkt = blockIdx.x;          // h*8 + kt
    const int h = hkt >> 3, kt = hkt & 7;
    const int tid = threadIdx.x;
    const int l = tid & 63, nq = tid >> 6;
    const int g = l >> 4, ml = l & 15;
    for (int t = 0; t < 4; ++t) {
        int nt = nq * 4 + t;
        uint16_t* dst = WF + (((size_t)(h * 8 + kt) * 16 + nt) * 64 + l) * 16;
        #pragma unroll
        for (int i = 0; i < 8; ++i) {
            float x = W[(size_t)h * 65536 + (size_t)(kt * 32 + g * 8 + i) * 256 + nt * 16 + ml];
            uint32_t hb = f2bf(x);
            float hf = __uint_as_float(hb << 16);
            uint32_t lb = f2bf(x - hf);
            dst[i] = (uint16_t)hb;
            dst[8 + i] = (uint16_t)lb;
        }
    }
}

// ---------------- kprepv: Wv [16][256][16] -> frag-ordered bf16 hi/lo ----------------
// WF[(h*8+kt)*64+lane][0..7]=hi, [8..15]=lo; elem i <-> Wv[h][32kt+8g+i][ml]
__global__ __launch_bounds__(64) void kprepv(const float* __restrict__ Wv,
                                             uint16_t* __restrict__ WF) {
    const int hkt = blockIdx.x;
    const int h = hkt >> 3, kt = hkt & 7;
    const int l = threadIdx.x;
    const int g = l >> 4, ml = l & 15;
    uint16_t* dst = WF + ((size_t)hkt * 64 + l) * 16;
    #pragma unroll
    for (int i = 0; i < 8; ++i) {
        float x = Wv[((size_t)h * 256 + kt * 32 + g * 8 + i) * 16 + ml];
        uint32_t hb = f2bf(x);
        float hf = __uint_as_float(hb << 16);
        uint32_t lb = f2bf(x - hf);
        dst[i] = (uint16_t)hb;
        dst[8 + i] = (uint16_t)lb;
    }
}

// ---------------- Kernel W: word-level MHSA + additive pooling ----------------
// grid = 1680, block = 256 (4 waves). All three GEMMs on MFMA; x pre-split in LDS.
__global__ __launch_bounds__(256) void kword(
    const int* __restrict__ cand, const int* __restrict__ clk,
    const float* __restrict__ emb, const uint16_t* __restrict__ Wfrag,
    const uint16_t* __restrict__ WvF, const float* __restrict__ WkT,
    const float* __restrict__ bk, const float* __restrict__ qv,
    float* __restrict__ mv_out, float* __restrict__ repr_out)
{
    __shared__ __align__(16) uint32_t xsb[32 * 256];  // 32 KB, split x, swizzled
    __shared__ __align__(16) uint32_t qs[32 * 256];   // 32 KB, split q; reused as kq in pooling
    __shared__ __align__(16) float ps[SS * 33];
    __shared__ __align__(16) float xv[32 * VV];
    __shared__ float scr[32];
    __shared__ float wts[32];

    const int item = blockIdx.x;
    const int tid  = threadIdx.x;
    const int w    = tid >> 6, lane = tid & 63;
    const int g    = lane >> 4, ml = lane & 15;
    const int* tok = (item < NCAND) ? cand + item * SS : clk + (item - NCAND) * SS;

    // stage x split (rows 30,31 zero)
    for (int p = tid; p < 32 * 64; p += 256) {
        int l = p >> 6, c = p & 63;
        float4 v = make_float4(0.f, 0.f, 0.f, 0.f);
        if (l < SS) v = *(const float4*)&emb[(size_t)tok[l] * EE + 4 * c];
        uint4 s;
        s.x = splitpack(v.x); s.y = splitpack(v.y);
        s.z = splitpack(v.z); s.w = splitpack(v.w);
        *(uint4*)&xsb[SWZW(l, c)] = s;
    }
    __syncthreads();

    float* mvg = mv_out + (size_t)item * SS * EE;

    for (int h = 0; h < HH; ++h) {
        // ---- phase A: Q = X @ Wq[h], 4-term split MFMA (bit-identical to r5) ----
        {
            f32x4 acc[2][4];
            #pragma unroll
            for (int a = 0; a < 2; ++a)
                #pragma unroll
                for (int b = 0; b < 4; ++b) acc[a][b] = (f32x4){0.f, 0.f, 0.f, 0.f};
            const uint16_t* WH = Wfrag + (size_t)h * (8 * 16 * 64 * 16);
            for (int kt = 0; kt < 8; ++kt) {
                bf16x8 ah[2], al[2];
                #pragma unroll
                for (int mt = 0; mt < 2; ++mt) {
                    int row = mt * 16 + ml;
                    int c0 = kt * 8 + 2 * g;
                    uint4 A0 = *(const uint4*)&xsb[SWZW(row, c0)];
                    uint4 A1 = *(const uint4*)&xsb[SWZW(row, c0 + 1)];
                    ah[mt] = hi8(A0, A1);
                    al[mt] = lo8(A0, A1);
                }
                #pragma unroll
                for (int n2 = 0; n2 < 4; ++n2) {
                    const uint16_t* bp = WH + (((size_t)kt * 16 + (w * 4 + n2)) * 64 + lane) * 16;
                    bf16x8 bh = *(const bf16x8*)bp;
                    bf16x8 bl = *(const bf16x8*)(bp + 8);
                    #pragma unroll
                    for (int mt = 0; mt < 2; ++mt) {
                        acc[mt][n2] = MFMA16(ah[mt], bh, acc[mt][n2]);
                        acc[mt][n2] = MFMA16(al[mt], bh, acc[mt][n2]);
                        acc[mt][n2] = MFMA16(ah[mt], bl, acc[mt][n2]);
                        acc[mt][n2] = MFMA16(al[mt], bl, acc[mt][n2]);
                    }
                }
            }
            // store q split into qs (SWZW layout)
            #pragma unroll
            for (int mt = 0; mt < 2; ++mt)
                #pragma unroll
                for (int n2 = 0; n2 < 4; ++n2) {
                    int col = (w * 4 + n2) * 16 + ml;
                    int chunk = col >> 2, sub = col & 3;
                    #pragma unroll
                    for (int r = 0; r < 4; ++r) {
                        int row = mt * 16 + g * 4 + r;
                        qs[row * 256 + (((chunk ^ (row & 7) ^ ((row & 24) >> 1)) << 2) | sub)] =
                            splitpack(acc[mt][n2][r]);
                    }
                }
        }
        __syncthreads();

        // ---- phase B: waves 0,1 scores (3-term MFMA + in-reg softmax); waves 2,3 xv ----
        if (w < 2) {
            f32x4 accs[2];
            accs[0] = (f32x4){0.f, 0.f, 0.f, 0.f};
            accs[1] = (f32x4){0.f, 0.f, 0.f, 0.f};
            const int arow = 16 * w + ml;
            for (int kt = 0; kt < 8; ++kt) {
                int c0 = kt * 8 + 2 * g;
                uint4 Q0 = *(const uint4*)&qs[SWZW(arow, c0)];
                uint4 Q1 = *(const uint4*)&qs[SWZW(arow, c0 + 1)];
                bf16x8 qh = hi8(Q0, Q1), ql = lo8(Q0, Q1);
                #pragma unroll
                for (int nt = 0; nt < 2; ++nt) {
                    int brow = nt * 16 + ml;
                    uint4 X0 = *(const uint4*)&xsb[SWZW(brow, c0)];
                    uint4 X1 = *(const uint4*)&xsb[SWZW(brow, c0 + 1)];
                    bf16x8 xh = hi8(X0, X1), xl = lo8(X0, X1);
                    accs[nt] = MFMA16(qh, xh, accs[nt]);
                    accs[nt] = MFMA16(ql, xh, accs[nt]);
                    accs[nt] = MFMA16(qh, xl, accs[nt]);
                }
            }
            #pragma unroll
            for (int r = 0; r < 4; ++r) {
                float v0 = accs[0][r] * 0.0625f;
                float v1 = (ml < 14) ? accs[1][r] * 0.0625f : -INFINITY;   // cols 30,31 masked
                float mx = fmaxf(v0, v1);
                mx = fmaxf(mx, __shfl_xor(mx, 1));
                mx = fmaxf(mx, __shfl_xor(mx, 2));
                mx = fmaxf(mx, __shfl_xor(mx, 4));
                mx = fmaxf(mx, __shfl_xor(mx, 8));
                float e0 = expf(v0 - mx);
                float e1 = (ml < 14) ? expf(v1 - mx) : 0.f;
                float s = e0 + e1;
                s += __shfl_xor(s, 1); s += __shfl_xor(s, 2);
                s += __shfl_xor(s, 4); s += __shfl_xor(s, 8);
                float inv = 1.f / s;
                int lrow = 16 * w + 4 * g + r;
                if (lrow < SS) {
                    ps[lrow * 33 + ml] = e0 * inv;
                    if (ml < 14) ps[lrow * 33 + 16 + ml] = e1 * inv;
                }
            }
        } else {
            f32x4 accv = (f32x4){0.f, 0.f, 0.f, 0.f};
            const int mt = w - 2;
            const int arow = 16 * mt + ml;
            for (int kt = 0; kt < 8; ++kt) {
                int c0 = kt * 8 + 2 * g;
                uint4 A0 = *(const uint4*)&xsb[SWZW(arow, c0)];
                uint4 A1 = *(const uint4*)&xsb[SWZW(arow, c0 + 1)];
                bf16x8 ah = hi8(A0, A1), al = lo8(A0, A1);
                const uint16_t* bp = WvF + (((size_t)h * 8 + kt) * 64 + lane) * 16;
                bf16x8 bh = *(const bf16x8*)bp;
                bf16x8 bl = *(const bf16x8*)(bp + 8);
                accv = MFMA16(ah, bh, accv);
                accv = MFMA16(al, bh, accv);
                accv = MFMA16(ah, bl, accv);
            }
            #pragma unroll
            for (int r = 0; r < 4; ++r) {
                int m = 16 * mt + 4 * g + r;
                if (m < SS) xv[m * 16 + ml] = accv[r];
            }
        }
        __syncthreads();

        // ---- PV ----
        if (tid < SS * 4) {
            const int l = tid >> 2, vq = tid & 3;
            float4 a = make_float4(0.f, 0.f, 0.f, 0.f);
            for (int m = 0; m < SS; ++m) {
                float pw = ps[l * 33 + m];
                float4 v4 = *(const float4*)&xv[m * 16 + vq * 4];
                a.x += pw * v4.x; a.y += pw * v4.y; a.z += pw * v4.z; a.w += pw * v4.w;
            }
            *(float4*)&mvg[l * 256 + h * 16 + vq * 4] = a;
        }
        // next phase A only writes qs (safe: qs readers passed the post-B barrier)
    }

    // ---- pooling ----
    __threadfence();
    __syncthreads();
    float* kq = (float*)qs;   // reuse as [30][204]
    if (tid < 200) {
        const int jq = tid % 50, lg = tid / 50;
        const int j0 = jq * 4;
        const int r0 = lg * 8;
        const int nr = (lg == 3) ? 6 : 8;
        float4 a[8];
        #pragma unroll
        for (int r = 0; r < 8; ++r) a[r] = make_float4(bk[j0], bk[j0+1], bk[j0+2], bk[j0+3]);
        for (int c = 0; c < 64; ++c) {
            float4 w0 = *(const float4*)&WkT[(j0 + 0) * 256 + 4 * c];
            float4 w1 = *(const float4*)&WkT[(j0 + 1) * 256 + 4 * c];
            float4 w2 = *(const float4*)&WkT[(j0 + 2) * 256 + 4 * c];
            float4 w3 = *(const float4*)&WkT[(j0 + 3) * 256 + 4 * c];
            #pragma unroll
            for (int r = 0; r < 8; ++r) {
                if (r < nr) {
                    float4 m4 = *(const float4*)&mvg[(r0 + r) * 256 + 4 * c];
                    a[r].x += dot4(m4, w0);
                    a[r].y += dot4(m4, w1);
                    a[r].z += dot4(m4, w2);
                    a[r].w += dot4(m4, w3);
                }
            }
        }
        #pragma unroll
        for (int r = 0; r < 8; ++r) {
            if (r < nr) {
                int row = r0 + r;
                kq[row * 204 + j0 + 0] = tanhf(a[r].x) * qv[j0 + 0];
                kq[row * 204 + j0 + 1] = tanhf(a[r].y) * qv[j0 + 1];
                kq[row * 204 + j0 + 2] = tanhf(a[r].z) * qv[j0 + 2];
                kq[row * 204 + j0 + 3] = tanhf(a[r].w) * qv[j0 + 3];
            }
        }
    }
    __syncthreads();
    if (tid < SS) {
        float a = 0.f;
        for (int j = 0; j < QD; ++j) a += kq[tid * 204 + j];
        scr[tid] = a * 0.0625f;
    }
    __syncthreads();
    if (tid == 0) {
        float mx = -INFINITY;
        for (int l = 0; l < SS; ++l) mx = fmaxf(mx, scr[l]);
        float sum = 0.f;
        for (int l = 0; l < SS; ++l) { float ev = expf(scr[l] - mx); wts[l] = ev; sum += ev; }
        float inv = 1.f / sum;
        for (int l = 0; l < SS; ++l) wts[l] *= inv;
    }
    __syncthreads();
    {
        float a = 0.f;
        for (int l = 0; l < SS; ++l) a += wts[l] * mvg[l * 256 + tid];
        repr_out[(size_t)item * EE + tid] = a;
    }
}

// ---------------- Kernel L: news-level logits ----------------
__global__ __launch_bounds__(128) void klogit(
    const float* __restrict__ repr, float* __restrict__ logits)
{
    const int bc = blockIdx.x;
    const int b  = bc / CDD;
    const int tid = threadIdx.x;
    __shared__ float cr[EE];
    for (int e = tid; e < EE; e += 128) cr[e] = repr[(size_t)bc * EE + e];
    __syncthreads();
    for (int h = tid; h < HIS; h += 128) {
        const float* hr = repr + (size_t)(NCAND + b * HIS + h) * EE;
        float a = 0.f;
        for (int e = 0; e < EE; ++e) a += cr[e] * hr[e];
        logits[bc * HIS + h] = a;
    }
}

// ---------------- Kernel S: greedy gumbel top-K selection (JAX-exact) ----------------
__global__ __launch_bounds__(128) void ksel(
    const float* __restrict__ logits, int* __restrict__ sel)
{
    const int bc = blockIdx.x, tid = threadIdx.x;
    __shared__ float lg[HIS];
    __shared__ float pert[HIS];
    for (int h = tid; h < HIS; h += 128) lg[h] = logits[bc * HIS + h];
    __syncthreads();
    for (int i = 0; i < KK; ++i) {
        uint32_t c0 = 0u, c1 = (uint32_t)i;
        tf2x32(0u, 42u, c0, c1);
        for (int h = tid; h < HIS; h += 128) {
            int n = bc * HIS + h;
            uint32_t x0, x1; int lane;
            if (n < 4000) { x0 = (uint32_t)n;          x1 = (uint32_t)(n + 4000); lane = 0; }
            else          { x0 = (uint32_t)(n - 4000); x1 = (uint32_t)n;          lane = 1; }
            tf2x32(c0, c1, x0, x1);
            uint32_t bits = lane ? x1 : x0;
            float f = __uint_as_float((bits >> 9) | 0x3F800000u) - 1.0f;
            const float TINY = 1.17549435e-38f;
            float u = fmaxf(f + TINY, TINY);
            float g = -logf(-logf(u));
            pert[h] = lg[h] + g;
        }
        __syncthreads();
        if (tid == 0) {
            float best = -INFINITY; int bi = 0;
            for (int h = 0; h < HIS; ++h)
                if (pert[h] > best) { best = pert[h]; bi = h; }
            sel[bc * KK + i] = bi;
            lg[bi] = -INFINITY;
        }
        __syncthreads();
    }
}

// ---------------- Kernel F1: fusion MHSA -> mvf (all GEMMs MFMA) ----------------
__global__ __launch_bounds__(256) void kfus(
    const float* __restrict__ mv, const int* __restrict__ sel,
    const uint16_t* __restrict__ Wfrag, const uint16_t* __restrict__ WvF,
    float* __restrict__ mvf)
{
    __shared__ __align__(16) uint32_t xsb[64 * 256];   // 64 KB split x, SWZ
    __shared__ __align__(16) uint16_t qsb[64 * 256];   // 32 KB q bf16
    __shared__ __align__(16) float ps[64 * 65];        // 16.6 KB
    __shared__ __align__(16) float xv[64 * 16];        // 4 KB

    const int item = blockIdx.x;
    const int tid  = threadIdx.x;
    const int w    = tid >> 6, lane = tid & 63;
    const int g    = lane >> 4, ml = lane & 15;
    const int bc = item / KK, k = item - bc * KK;
    const int b  = bc / CDD;
    const int sh = sel[bc * KK + k];
    const float* cmv = mv + (size_t)bc * SS * EE;
    const float* hmv = mv + (size_t)(NCAND + b * HIS + sh) * SS * EE;
    float* out = mvf + (size_t)item * TT * EE;

    for (int p = tid; p < 64 * 64; p += 256) {
        int l = p >> 6, c = p & 63;
        float4 v = make_float4(0.f, 0.f, 0.f, 0.f);
        if (l < SS)                v = *(const float4*)&cmv[l * 256 + 4 * c];
        else if (l > SS && l < TT) v = *(const float4*)&hmv[(l - SS - 1) * 256 + 4 * c];
        uint4 s;
        s.x = splitpack(v.x); s.y = splitpack(v.y);
        s.z = splitpack(v.z); s.w = splitpack(v.w);
        *(uint4*)&xsb[SWZ(l, c)] = s;
    }
    __syncthreads();

    for (int h = 0; h < HH; ++h) {
        // ---- phase A: Q = X @ Wq_i[h], 3-term split MFMA -> qsb (bf16) ----
        {
            f32x4 acc[4][4];
            #pragma unroll
            for (int a = 0; a < 4; ++a)
                #pragma unroll
                for (int b2 = 0; b2 < 4; ++b2) acc[a][b2] = (f32x4){0.f, 0.f, 0.f, 0.f};
            const uint16_t* WH = Wfrag + (size_t)h * (8 * 16 * 64 * 16);
            for (int kt = 0; kt < 8; ++kt) {
                bf16x8 ah[4], al[4];
                #pragma unroll
                for (int mt = 0; mt < 4; ++mt) {
                    int row = mt * 16 + ml;
                    int c0 = kt * 8 + 2 * g;
                    uint4 A0 = *(const uint4*)&xsb[SWZ(row, c0)];
                    uint4 A1 = *(const uint4*)&xsb[SWZ(row, c0 + 1)];
                    ah[mt] = hi8(A0, A1);
                    al[mt] = lo8(A0, A1);
                }
                #pragma unroll
                for (int n2 = 0; n2 < 4; ++n2) {
                    const uint16_t* bp = WH + (((size_t)kt * 16 + (w * 4 + n2)) * 64 + lane) * 16;
                    bf16x8 bh = *(const bf16x8*)bp;
                    bf16x8 bl = *(const bf16x8*)(bp + 8);
                    #pragma unroll
                    for (int mt = 0; mt < 4; ++mt) {
                        acc[mt][n2] = MFMA16(ah[mt], bh, acc[mt][n2]);
                        acc[mt][n2] = MFMA16(al[mt], bh, acc[mt][n2]);
                        acc[mt][n2] = MFMA16(ah[mt], bl, acc[mt][n2]);
                    }
                }
            }
            // write q (bf16) -> qsb: pair even/odd cols via shfl_xor(1)
            #pragma unroll
            for (int mt = 0; mt < 4; ++mt)
                #pragma unroll
                for (int n2 = 0; n2 < 4; ++n2) {
                    #pragma unroll
                    for (int r = 0; r < 4; ++r) {
                        uint32_t mb = f2bf(acc[mt][n2][r]);
                        uint32_t ob = (uint32_t)__shfl_xor((int)mb, 1);
                        if ((ml & 1) == 0) {
                            int col0 = (w * 4 + n2) * 16 + ml;
                            int row = mt * 16 + g * 4 + r;
                            int idx = row * 256 + ((((col0 >> 3) ^ (row & 7)) << 3) | (col0 & 7));
                            *(uint32_t*)&qsb[idx] = mb | (ob << 16);
                        }
                    }
                }
        }
        __syncthreads();

        // ---- phase B: scores (1-term bf16 MFMA) + xv (1-term) + in-reg softmax ----
        {
            f32x4 accs[4];
            #pragma unroll
            for (int nt = 0; nt < 4; ++nt) accs[nt] = (f32x4){0.f, 0.f, 0.f, 0.f};
            f32x4 accv = (f32x4){0.f, 0.f, 0.f, 0.f};
            const int arow = 16 * w + ml;
            for (int kt = 0; kt < 8; ++kt) {
                int cq = 4 * kt + g;
                bf16x8 qh = *(const bf16x8*)&qsb[arow * 256 + ((cq ^ (arow & 7)) << 3)];
                int c0 = kt * 8 + 2 * g;
                #pragma unroll
                for (int nt = 0; nt < 4; ++nt) {
                    int brow = 16 * nt + ml;
                    uint4 X0 = *(const uint4*)&xsb[SWZ(brow, c0)];
                    uint4 X1 = *(const uint4*)&xsb[SWZ(brow, c0 + 1)];
                    accs[nt] = MFMA16(qh, hi8(X0, X1), accs[nt]);
                }
                // xv: A = x rows 16w.., B = WvF
                uint4 A0 = *(const uint4*)&xsb[SWZ(arow, c0)];
                uint4 A1 = *(const uint4*)&xsb[SWZ(arow, c0 + 1)];
                bf16x8 bh = *(const bf16x8*)&WvF[(((size_t)h * 8 + kt) * 64 + lane) * 16];
                accv = MFMA16(hi8(A0, A1), bh, accv);
            }
            // softmax rows l = 16w+4g+r over cols 0..60
            #pragma unroll
            for (int r = 0; r < 4; ++r) {
                float v0 = accs[0][r] * 0.0625f;
                float v1 = accs[1][r] * 0.0625f;
                float v2 = accs[2][r] * 0.0625f;
                float v3 = (ml < 13) ? accs[3][r] * 0.0625f : -INFINITY;  // cols 61..63 masked
                float mx = fmaxf(fmaxf(v0, v1), fmaxf(v2, v3));
                mx = fmaxf(mx, __shfl_xor(mx, 1));
                mx = fmaxf(mx, __shfl_xor(mx, 2));
                mx = fmaxf(mx, __shfl_xor(mx, 4));
                mx = fmaxf(mx, __shfl_xor(mx, 8));
                float e0 = expf(v0 - mx);
                float e1 = expf(v1 - mx);
                float e2 = expf(v2 - mx);
                float e3 = (ml < 13) ? expf(v3 - mx) : 0.f;
                float s = e0 + e1 + e2 + e3;
                s += __shfl_xor(s, 1); s += __shfl_xor(s, 2);
                s += __shfl_xor(s, 4); s += __shfl_xor(s, 8);
                float inv = 1.f / s;
                int lrow = 16 * w + 4 * g + r;
                if (lrow < TT) {
                    ps[lrow * 65 + ml]      = e0 * inv;
                    ps[lrow * 65 + 16 + ml] = e1 * inv;
                    ps[lrow * 65 + 32 + ml] = e2 * inv;
                    if (ml < 13) ps[lrow * 65 + 48 + ml] = e3 * inv;
                }
                int m = 16 * w + 4 * g + r;
                if (m < TT) xv[m * 16 + ml] = accv[r];
            }
        }
        __syncthreads();

        // ---- PV ----
        if (lane < TT) {
            const int l = lane, vq = w;
            float4 a = make_float4(0.f, 0.f, 0.f, 0.f);
            for (int m = 0; m < TT; ++m) {
                float pw = ps[l * 65 + m];
                float4 x4 = *(const float4*)&xv[m * 16 + vq * 4];
                a.x += pw * x4.x; a.y += pw * x4.y; a.z += pw * x4.z; a.w += pw * x4.w;
            }
            *(float4*)&out[l * 256 + h * 16 + vq * 4] = a;
        }
        // next phase A only writes qsb (safe: qsb readers passed the post-B barrier)
    }
}

// ---------------- Kernel F2: fusion pooling -> fvec ----------------
__global__ __launch_bounds__(256) void kpoolf(
    const float* __restrict__ mvf, const float* __restrict__ WkT,
    const float* __restrict__ bk, const float* __restrict__ qv,
    float* __restrict__ fvec)
{
    __shared__ float kq[TT * 201];
    __shared__ float scr[TT];
    __shared__ float wts[TT];
    const int item = blockIdx.x, tid = threadIdx.x;
    const float* src = mvf + (size_t)item * TT * EE;
    for (int p = tid; p < TT * 50; p += 256) {
        int l = p / 50, jq = p - l * 50;
        int j0 = jq * 4;
        float4 a = make_float4(bk[j0], bk[j0+1], bk[j0+2], bk[j0+3]);
        const float* mr = src + l * 256;
        for (int c = 0; c < 64; ++c) {
            float4 m4 = *(const float4*)&mr[4 * c];
            a.x += dot4(m4, *(const float4*)&WkT[(j0+0) * 256 + 4*c]);
            a.y += dot4(m4, *(const float4*)&WkT[(j0+1) * 256 + 4*c]);
            a.z += dot4(m4, *(const float4*)&WkT[(j0+2) * 256 + 4*c]);
            a.w += dot4(m4, *(const float4*)&WkT[(j0+3) * 256 + 4*c]);
        }
        kq[l*201 + j0 + 0] = tanhf(a.x) * qv[j0+0];
        kq[l*201 + j0 + 1] = tanhf(a.y) * qv[j0+1];
        kq[l*201 + j0 + 2] = tanhf(a.z) * qv[j0+2];
        kq[l*201 + j0 + 3] = tanhf(a.w) * qv[j0+3];
    }
    __syncthreads();
    if (tid < TT) {
        float a = 0.f;
        for (int j = 0; j < QD; ++j) a += kq[tid * 201 + j];
        scr[tid] = a * 0.0625f;
    }
    __syncthreads();
    if (tid == 0) {
        float mx = -INFINITY;
        for (int l = 0; l < TT; ++l) mx = fmaxf(mx, scr[l]);
        float sum = 0.f;
        for (int l = 0; l < TT; ++l) { float ev = expf(scr[l] - mx); wts[l] = ev; sum += ev; }
        float inv = 1.f / sum;
        for (int l = 0; l < TT; ++l) wts[l] *= inv;
    }
    __syncthreads();
    float a = 0.f;
    for (int l = 0; l < TT; ++l) a += wts[l] * src[l * 256 + tid];
    fvec[(size_t)item * EE + tid] = a;
}

// ---------------- Kernel Z: mean over K, score, log_softmax -> FP32 out ----------------
__global__ __launch_bounds__(256) void kfinal(
    const float* __restrict__ fvec, const float* __restrict__ Wl,
    const float* __restrict__ bl, float* __restrict__ out)
{
    const int b = blockIdx.x, tid = threadIdx.x;
    __shared__ float red[256];
    __shared__ float sc5[CDD];
    for (int c = 0; c < CDD; ++c) {
        size_t base = ((size_t)(b * CDD + c) * KK) * EE + tid;
        float f = (fvec[base] + fvec[base + EE] + fvec[base + 2 * EE]) * (1.f / 3.f);
        red[tid] = f * Wl[tid];
        __syncthreads();
        for (int s = 128; s > 0; s >>= 1) {
            if (tid < s) red[tid] += red[tid + s];
            __syncthreads();
        }
        if (tid == 0) sc5[c] = red[0] + bl[0];
        __syncthreads();
    }
    if (tid == 0) {
        float mx = -INFINITY;
        for (int c = 0; c < CDD; ++c) mx = fmaxf(mx, sc5[c]);
        float sum = 0.f;
        for (int c = 0; c < CDD; ++c) sum += expf(sc5[c] - mx);
        float lse = mx + logf(sum);
        for (int c = 0; c < CDD; ++c) out[b * CDD + c] = sc5[c] - lse;
    }
}

extern "C" void kernel_launch(void* const* d_in, const int* in_sizes, int n_in,
                              void* d_out, int out_size, void* d_ws, size_t ws_size,
                              hipStream_t stream) {
    const int*   cand = (const int*)d_in[0];
    const int*   clk  = (const int*)d_in[1];
    const float* emb  = (const float*)d_in[5];
    const float* Wq_w = (const float*)d_in[6];
    const float* Wv_w = (const float*)d_in[7];
    const float* Wk_w = (const float*)d_in[8];
    const float* bk_w = (const float*)d_in[9];
    const float* q_w  = (const float*)d_in[10];
    const float* Wq_i = (const float*)d_in[11];
    const float* Wv_i = (const float*)d_in[12];
    const float* Wk_i = (const float*)d_in[13];
    const float* bk_i = (const float*)d_in[14];
    const float* q_i  = (const float*)d_in[15];
    const float* Wl   = (const float*)d_in[16];
    const float* bl   = (const float*)d_in[17];

    // workspace layout (float units)
    float* ws     = (float*)d_ws;
    float* mv     = ws;                                   // 12,902,400
    float* repr   = mv   + (size_t)NITEM * SS * EE;       // 430,080
    float* mvf    = repr + (size_t)NITEM * EE;            // 3,747,840
    float* fvec   = mvf  + (size_t)NFUS * TT * EE;        // 61,440
    float* logits = fvec + (size_t)NFUS * EE;             // 8,000
    float* WkTw   = logits + NCAND * HIS;                 // 51,200
    float* WkTi   = WkTw + QD * EE;                       // 51,200
    int*   sel    = (int*)(WkTi + QD * EE);               // 256
    uint16_t* WfW = (uint16_t*)((float*)sel + 256);       // 2,097,152 u16
    uint16_t* WfI = WfW + (size_t)16 * 8 * 16 * 64 * 16;  // 2,097,152 u16
    uint16_t* WvFw = WfI + (size_t)16 * 8 * 16 * 64 * 16; // 131,072 u16
    uint16_t* WvFi = WvFw + (size_t)16 * 8 * 64 * 16;     // 131,072 u16

    ktrans<<<dim3(QD),    dim3(256), 0, stream>>>(Wk_w, WkTw);
    ktrans<<<dim3(QD),    dim3(256), 0, stream>>>(Wk_i, WkTi);
    kprep <<<dim3(128),   dim3(256), 0, stream>>>(Wq_w, WfW);
    kprep <<<dim3(128),   dim3(256), 0, stream>>>(Wq_i, WfI);
    kprepv<<<dim3(128),   dim3(64),  0, stream>>>(Wv_w, WvFw);
    kprepv<<<dim3(128),   dim3(64),  0, stream>>>(Wv_i, WvFi);
    kword <<<dim3(NITEM), dim3(256), 0, stream>>>(cand, clk, emb, WfW, WvFw, WkTw, bk_w, q_w, mv, repr);
    klogit<<<dim3(NCAND), dim3(128), 0, stream>>>(repr, logits);
    ksel  <<<dim3(NCAND), dim3(128), 0, stream>>>(logits, sel);
    kfus  <<<dim3(NFUS),  dim3(256), 0, stream>>>(mv, sel, WfI, WvFi, mvf);
    kpoolf<<<dim3(NFUS),  dim3(256), 0, stream>>>(mvf, WkTi, bk_i, q_i, fvec);
    kfinal<<<dim3(BB),    dim3(256), 0, stream>>>(fvec, Wl, bl, (float*)d_out);
}

// Round 10
// 2148.825 us; speedup vs baseline: 1.0024x; 1.0024x over previous
//
#include <hip/hip_runtime.h>
#include <hip/hip_bf16.h>
#include <stdint.h>

// Problem dims
#define BB    16
#define CDD   5
#define HIS   100
#define SS    30
#define EE    256
#define HH    16
#define VV    16
#define QD    200
#define KK    3
#define TT    61     // 2*S+1
#define NCAND 80     // B*CDD
#define NITEM 1680   // NCAND + B*HIS
#define NFUS  240    // B*CDD*K

typedef __attribute__((ext_vector_type(8))) short bf16x8;
typedef __attribute__((ext_vector_type(4))) float f32x4;
#define MFMA16(a, b, c) __builtin_amdgcn_mfma_f32_16x16x32_bf16(a, b, c, 0, 0, 0)

// kfus swizzle (u32/float element index; 16B chunk c in [0,64))
__device__ __forceinline__ int SWZ(int l, int c) { return l * 256 + (((c) ^ (l & 7)) << 2); }
// kword swizzle: adds (l&24)>>1 so rows differing by 8 map to different bank quads
__device__ __forceinline__ int SWZW(int l, int c) {
    return l * 256 + (((c ^ (l & 7) ^ ((l & 24) >> 1))) << 2);
}

__device__ __forceinline__ float dot4(float4 a, float4 b) {
    return a.x * b.x + a.y * b.y + a.z * b.z + a.w * b.w;
}
__device__ __forceinline__ uint32_t f2bf(float x) {   // RNE f32->bf16 bits
    uint32_t u = __float_as_uint(x);
    return (u + 0x7fffu + ((u >> 16) & 1u)) >> 16;
}
// split x into bf16 hi/lo, packed (hi<<16)|lo
__device__ __forceinline__ uint32_t splitpack(float x) {
    uint32_t hb = f2bf(x);
    float hf = __uint_as_float(hb << 16);
    uint32_t lb = f2bf(x - hf);
    return (hb << 16) | lb;
}
union b8u4 { uint4 u; bf16x8 b; };
__device__ __forceinline__ bf16x8 hi8(uint4 a, uint4 b) {  // 8 packed u32 -> hi bf16x8
    b8u4 cv;
    cv.u.x = (a.x >> 16) | (a.y & 0xffff0000u);
    cv.u.y = (a.z >> 16) | (a.w & 0xffff0000u);
    cv.u.z = (b.x >> 16) | (b.y & 0xffff0000u);
    cv.u.w = (b.z >> 16) | (b.w & 0xffff0000u);
    return cv.b;
}
__device__ __forceinline__ bf16x8 lo8(uint4 a, uint4 b) {
    b8u4 cv;
    cv.u.x = (a.x & 0xffffu) | (a.y << 16);
    cv.u.y = (a.z & 0xffffu) | (a.w << 16);
    cv.u.z = (b.x & 0xffffu) | (b.y << 16);
    cv.u.w = (b.z & 0xffffu) | (b.w << 16);
    return cv.b;
}

// ---------------- Threefry2x32 (exact JAX reproduction) ----------------
__device__ __forceinline__ uint32_t rotl32(uint32_t v, int r) {
    return (v << r) | (v >> (32 - r));
}
__device__ __forceinline__ void tf2x32(uint32_t k0, uint32_t k1, uint32_t& x0, uint32_t& x1) {
    uint32_t k2 = k0 ^ k1 ^ 0x1BD11BDAu;
    x0 += k0; x1 += k1;
    const int r0[4] = {13, 15, 26, 6}, r1[4] = {17, 29, 16, 24};
    #pragma unroll
    for (int i = 0; i < 4; ++i) { x0 += x1; x1 = rotl32(x1, r0[i]); x1 ^= x0; }
    x0 += k1; x1 += k2 + 1u;
    #pragma unroll
    for (int i = 0; i < 4; ++i) { x0 += x1; x1 = rotl32(x1, r1[i]); x1 ^= x0; }
    x0 += k2; x1 += k0 + 2u;
    #pragma unroll
    for (int i = 0; i < 4; ++i) { x0 += x1; x1 = rotl32(x1, r0[i]); x1 ^= x0; }
    x0 += k0; x1 += k1 + 3u;
    #pragma unroll
    for (int i = 0; i < 4; ++i) { x0 += x1; x1 = rotl32(x1, r1[i]); x1 ^= x0; }
    x0 += k1; x1 += k2 + 4u;
    #pragma unroll
    for (int i = 0; i < 4; ++i) { x0 += x1; x1 = rotl32(x1, r0[i]); x1 ^= x0; }
    x0 += k2; x1 += k0 + 5u;
}

// ---------------- ktrans: Wk [256][200] -> WkT [200][256] ----------------
__global__ __launch_bounds__(256) void ktrans(const float* __restrict__ Wk,
                                              float* __restrict__ WkT) {
    int j = blockIdx.x;
    int r = threadIdx.x;
    WkT[j * 256 + r] = Wk[r * QD + j];
}

// ---------------- kprep: Wq [16][256][256] fp32 -> fragment-ordered bf16 hi/lo ----
// WF[((h*8+kt)*16+nt)*64+lane][0..7]=hi, [8..15]=lo; elem i <-> W[h][32kt+8g+i][16nt+ml]
__global__ __launch_bounds__(256) void kprep(const float* __restrict__ W,
                                             uint16_t* __restrict__ WF) {
    const int hkt = blockIdx.x;          // h*8 + kt
    const int h = hkt >> 3, kt = hkt & 7;
    const int tid = threadIdx.x;
    const int l = tid & 63, nq = tid >> 6;
    const int g = l >> 4, ml = l & 15;
    for (int t = 0; t < 4; ++t) {
        int nt = nq * 4 + t;
        uint16_t* dst = WF + (((size_t)(h * 8 + kt) * 16 + nt) * 64 + l) * 16;
        #pragma unroll
        for (int i = 0; i < 8; ++i) {
            float x = W[(size_t)h * 65536 + (size_t)(kt * 32 + g * 8 + i) * 256 + nt * 16 + ml];
            uint32_t hb = f2bf(x);
            float hf = __uint_as_float(hb << 16);
            uint32_t lb = f2bf(x - hf);
            dst[i] = (uint16_t)hb;
            dst[8 + i] = (uint16_t)lb;
        }
    }
}

// ---------------- kprepv: Wv [16][256][16] -> frag-ordered bf16 hi/lo ----------------
// WF[(h*8+kt)*64+lane][0..7]=hi, [8..15]=lo; elem i <-> Wv[h][32kt+8g+i][ml]
__global__ __launch_bounds__(64) void kprepv(const float* __restrict__ Wv,
                                             uint16_t* __restrict__ WF) {
    const int hkt = blockIdx.x;
    const int h = hkt >> 3, kt = hkt & 7;
    const int l = threadIdx.x;
    const int g = l >> 4, ml = l & 15;
    uint16_t* dst = WF + ((size_t)hkt * 64 + l) * 16;
    #pragma unroll
    for (int i = 0; i < 8; ++i) {
        float x = Wv[((size_t)h * 256 + kt * 32 + g * 8 + i) * 16 + ml];
        uint32_t hb = f2bf(x);
        float hf = __uint_as_float(hb << 16);
        uint32_t lb = f2bf(x - hf);
        dst[i] = (uint16_t)hb;
        dst[8 + i] = (uint16_t)lb;
    }
}

// ---------------- Kernel W: word-level MHSA + additive pooling ----------------
// grid = 1680, block = 256 (4 waves). All three GEMMs on MFMA; x pre-split in LDS.
__global__ __launch_bounds__(256) void kword(
    const int* __restrict__ cand, const int* __restrict__ clk,
    const float* __restrict__ emb, const uint16_t* __restrict__ Wfrag,
    const uint16_t* __restrict__ WvF, const float* __restrict__ WkT,
    const float* __restrict__ bk, const float* __restrict__ qv,
    float* __restrict__ mv_out, float* __restrict__ repr_out)
{
    __shared__ __align__(16) uint32_t xsb[32 * 256];  // 32 KB, split x, swizzled
    __shared__ __align__(16) uint32_t qs[32 * 256];   // 32 KB, split q; reused as kq in pooling
    __shared__ __align__(16) float ps[SS * 33];
    __shared__ __align__(16) float xv[32 * VV];
    __shared__ float scr[32];
    __shared__ float wts[32];

    const int item = blockIdx.x;
    const int tid  = threadIdx.x;
    const int w    = tid >> 6, lane = tid & 63;
    const int g    = lane >> 4, ml = lane & 15;
    const int* tok = (item < NCAND) ? cand + item * SS : clk + (item - NCAND) * SS;

    // stage x split (rows 30,31 zero)
    for (int p = tid; p < 32 * 64; p += 256) {
        int l = p >> 6, c = p & 63;
        float4 v = make_float4(0.f, 0.f, 0.f, 0.f);
        if (l < SS) v = *(const float4*)&emb[(size_t)tok[l] * EE + 4 * c];
        uint4 s;
        s.x = splitpack(v.x); s.y = splitpack(v.y);
        s.z = splitpack(v.z); s.w = splitpack(v.w);
        *(uint4*)&xsb[SWZW(l, c)] = s;
    }
    __syncthreads();

    float* mvg = mv_out + (size_t)item * SS * EE;

    for (int h = 0; h < HH; ++h) {
        // ---- phase A: Q = X @ Wq[h], 4-term split MFMA (bit-identical to r5) ----
        {
            f32x4 acc[2][4];
            #pragma unroll
            for (int a = 0; a < 2; ++a)
                #pragma unroll
                for (int b = 0; b < 4; ++b) acc[a][b] = (f32x4){0.f, 0.f, 0.f, 0.f};
            const uint16_t* WH = Wfrag + (size_t)h * (8 * 16 * 64 * 16);
            for (int kt = 0; kt < 8; ++kt) {
                bf16x8 ah[2], al[2];
                #pragma unroll
                for (int mt = 0; mt < 2; ++mt) {
                    int row = mt * 16 + ml;
                    int c0 = kt * 8 + 2 * g;
                    uint4 A0 = *(const uint4*)&xsb[SWZW(row, c0)];
                    uint4 A1 = *(const uint4*)&xsb[SWZW(row, c0 + 1)];
                    ah[mt] = hi8(A0, A1);
                    al[mt] = lo8(A0, A1);
                }
                #pragma unroll
                for (int n2 = 0; n2 < 4; ++n2) {
                    const uint16_t* bp = WH + (((size_t)kt * 16 + (w * 4 + n2)) * 64 + lane) * 16;
                    bf16x8 bh = *(const bf16x8*)bp;
                    bf16x8 bl = *(const bf16x8*)(bp + 8);
                    #pragma unroll
                    for (int mt = 0; mt < 2; ++mt) {
                        acc[mt][n2] = MFMA16(ah[mt], bh, acc[mt][n2]);
                        acc[mt][n2] = MFMA16(al[mt], bh, acc[mt][n2]);
                        acc[mt][n2] = MFMA16(ah[mt], bl, acc[mt][n2]);
                        acc[mt][n2] = MFMA16(al[mt], bl, acc[mt][n2]);
                    }
                }
            }
            // store q split into qs (SWZW layout)
            #pragma unroll
            for (int mt = 0; mt < 2; ++mt)
                #pragma unroll
                for (int n2 = 0; n2 < 4; ++n2) {
                    int col = (w * 4 + n2) * 16 + ml;
                    int chunk = col >> 2, sub = col & 3;
                    #pragma unroll
                    for (int r = 0; r < 4; ++r) {
                        int row = mt * 16 + g * 4 + r;
                        qs[row * 256 + (((chunk ^ (row & 7) ^ ((row & 24) >> 1)) << 2) | sub)] =
                            splitpack(acc[mt][n2][r]);
                    }
                }
        }
        __syncthreads();

        // ---- phase B: waves 0,1 scores (3-term MFMA + in-reg softmax); waves 2,3 xv ----
        if (w < 2) {
            f32x4 accs[2];
            accs[0] = (f32x4){0.f, 0.f, 0.f, 0.f};
            accs[1] = (f32x4){0.f, 0.f, 0.f, 0.f};
            const int arow = 16 * w + ml;
            for (int kt = 0; kt < 8; ++kt) {
                int c0 = kt * 8 + 2 * g;
                uint4 Q0 = *(const uint4*)&qs[SWZW(arow, c0)];
                uint4 Q1 = *(const uint4*)&qs[SWZW(arow, c0 + 1)];
                bf16x8 qh = hi8(Q0, Q1), ql = lo8(Q0, Q1);
                #pragma unroll
                for (int nt = 0; nt < 2; ++nt) {
                    int brow = nt * 16 + ml;
                    uint4 X0 = *(const uint4*)&xsb[SWZW(brow, c0)];
                    uint4 X1 = *(const uint4*)&xsb[SWZW(brow, c0 + 1)];
                    bf16x8 xh = hi8(X0, X1), xl = lo8(X0, X1);
                    accs[nt] = MFMA16(qh, xh, accs[nt]);
                    accs[nt] = MFMA16(ql, xh, accs[nt]);
                    accs[nt] = MFMA16(qh, xl, accs[nt]);
                }
            }
            #pragma unroll
            for (int r = 0; r < 4; ++r) {
                float v0 = accs[0][r] * 0.0625f;
                float v1 = (ml < 14) ? accs[1][r] * 0.0625f : -INFINITY;   // cols 30,31 masked
                float mx = fmaxf(v0, v1);
                mx = fmaxf(mx, __shfl_xor(mx, 1));
                mx = fmaxf(mx, __shfl_xor(mx, 2));
                mx = fmaxf(mx, __shfl_xor(mx, 4));
                mx = fmaxf(mx, __shfl_xor(mx, 8));
                float e0 = expf(v0 - mx);
                float e1 = (ml < 14) ? expf(v1 - mx) : 0.f;
                float s = e0 + e1;
                s += __shfl_xor(s, 1); s += __shfl_xor(s, 2);
                s += __shfl_xor(s, 4); s += __shfl_xor(s, 8);
                float inv = 1.f / s;
                int lrow = 16 * w + 4 * g + r;
                if (lrow < SS) {
                    ps[lrow * 33 + ml] = e0 * inv;
                    if (ml < 14) ps[lrow * 33 + 16 + ml] = e1 * inv;
                }
            }
        } else {
            f32x4 accv = (f32x4){0.f, 0.f, 0.f, 0.f};
            const int mt = w - 2;
            const int arow = 16 * mt + ml;
            for (int kt = 0; kt < 8; ++kt) {
                int c0 = kt * 8 + 2 * g;
                uint4 A0 = *(const uint4*)&xsb[SWZW(arow, c0)];
                uint4 A1 = *(const uint4*)&xsb[SWZW(arow, c0 + 1)];
                bf16x8 ah = hi8(A0, A1), al = lo8(A0, A1);
                const uint16_t* bp = WvF + (((size_t)h * 8 + kt) * 64 + lane) * 16;
                bf16x8 bh = *(const bf16x8*)bp;
                bf16x8 bl = *(const bf16x8*)(bp + 8);
                accv = MFMA16(ah, bh, accv);
                accv = MFMA16(al, bh, accv);
                accv = MFMA16(ah, bl, accv);
            }
            #pragma unroll
            for (int r = 0; r < 4; ++r) {
                int m = 16 * mt + 4 * g + r;
                if (m < SS) xv[m * 16 + ml] = accv[r];
            }
        }
        __syncthreads();

        // ---- PV ----
        if (tid < SS * 4) {
            const int l = tid >> 2, vq = tid & 3;
            float4 a = make_float4(0.f, 0.f, 0.f, 0.f);
            for (int m = 0; m < SS; ++m) {
                float pw = ps[l * 33 + m];
                float4 v4 = *(const float4*)&xv[m * 16 + vq * 4];
                a.x += pw * v4.x; a.y += pw * v4.y; a.z += pw * v4.z; a.w += pw * v4.w;
            }
            *(float4*)&mvg[l * 256 + h * 16 + vq * 4] = a;
        }
        // next phase A only writes qs (safe: qs readers passed the post-B barrier)
    }

    // ---- pooling ----
    __threadfence();
    __syncthreads();
    float* kq = (float*)qs;   // reuse as [30][204]
    if (tid < 200) {
        const int jq = tid % 50, lg = tid / 50;
        const int j0 = jq * 4;
        const int r0 = lg * 8;
        const int nr = (lg == 3) ? 6 : 8;
        float4 a[8];
        #pragma unroll
        for (int r = 0; r < 8; ++r) a[r] = make_float4(bk[j0], bk[j0+1], bk[j0+2], bk[j0+3]);
        for (int c = 0; c < 64; ++c) {
            float4 w0 = *(const float4*)&WkT[(j0 + 0) * 256 + 4 * c];
            float4 w1 = *(const float4*)&WkT[(j0 + 1) * 256 + 4 * c];
            float4 w2 = *(const float4*)&WkT[(j0 + 2) * 256 + 4 * c];
            float4 w3 = *(const float4*)&WkT[(j0 + 3) * 256 + 4 * c];
            #pragma unroll
            for (int r = 0; r < 8; ++r) {
                if (r < nr) {
                    float4 m4 = *(const float4*)&mvg[(r0 + r) * 256 + 4 * c];
                    a[r].x += dot4(m4, w0);
                    a[r].y += dot4(m4, w1);
                    a[r].z += dot4(m4, w2);
                    a[r].w += dot4(m4, w3);
                }
            }
        }
        #pragma unroll
        for (int r = 0; r < 8; ++r) {
            if (r < nr) {
                int row = r0 + r;
                kq[row * 204 + j0 + 0] = tanhf(a[r].x) * qv[j0 + 0];
                kq[row * 204 + j0 + 1] = tanhf(a[r].y) * qv[j0 + 1];
                kq[row * 204 + j0 + 2] = tanhf(a[r].z) * qv[j0 + 2];
                kq[row * 204 + j0 + 3] = tanhf(a[r].w) * qv[j0 + 3];
            }
        }
    }
    __syncthreads();
    if (tid < SS) {
        float a = 0.f;
        for (int j = 0; j < QD; ++j) a += kq[tid * 204 + j];
        scr[tid] = a * 0.0625f;
    }
    __syncthreads();
    if (tid == 0) {
        float mx = -INFINITY;
        for (int l = 0; l < SS; ++l) mx = fmaxf(mx, scr[l]);
        float sum = 0.f;
        for (int l = 0; l < SS; ++l) { float ev = expf(scr[l] - mx); wts[l] = ev; sum += ev; }
        float inv = 1.f / sum;
        for (int l = 0; l < SS; ++l) wts[l] *= inv;
    }
    __syncthreads();
    {
        float a = 0.f;
        for (int l = 0; l < SS; ++l) a += wts[l] * mvg[l * 256 + tid];
        repr_out[(size_t)item * EE + tid] = a;
    }
}

// ---------------- Kernel L: news-level logits ----------------
__global__ __launch_bounds__(128) void klogit(
    const float* __restrict__ repr, float* __restrict__ logits)
{
    const int bc = blockIdx.x;
    const int b  = bc / CDD;
    const int tid = threadIdx.x;
    __shared__ float cr[EE];
    for (int e = tid; e < EE; e += 128) cr[e] = repr[(size_t)bc * EE + e];
    __syncthreads();
    for (int h = tid; h < HIS; h += 128) {
        const float* hr = repr + (size_t)(NCAND + b * HIS + h) * EE;
        float a = 0.f;
        for (int e = 0; e < EE; ++e) a += cr[e] * hr[e];
        logits[bc * HIS + h] = a;
    }
}

// ---------------- Kernel S: greedy gumbel top-K selection (JAX-exact) ----------------
__global__ __launch_bounds__(128) void ksel(
    const float* __restrict__ logits, int* __restrict__ sel)
{
    const int bc = blockIdx.x, tid = threadIdx.x;
    __shared__ float lg[HIS];
    __shared__ float pert[HIS];
    for (int h = tid; h < HIS; h += 128) lg[h] = logits[bc * HIS + h];
    __syncthreads();
    for (int i = 0; i < KK; ++i) {
        uint32_t c0 = 0u, c1 = (uint32_t)i;
        tf2x32(0u, 42u, c0, c1);
        for (int h = tid; h < HIS; h += 128) {
            int n = bc * HIS + h;
            uint32_t x0, x1; int lane;
            if (n < 4000) { x0 = (uint32_t)n;          x1 = (uint32_t)(n + 4000); lane = 0; }
            else          { x0 = (uint32_t)(n - 4000); x1 = (uint32_t)n;          lane = 1; }
            tf2x32(c0, c1, x0, x1);
            uint32_t bits = lane ? x1 : x0;
            float f = __uint_as_float((bits >> 9) | 0x3F800000u) - 1.0f;
            const float TINY = 1.17549435e-38f;
            float u = fmaxf(f + TINY, TINY);
            float g = -logf(-logf(u));
            pert[h] = lg[h] + g;
        }
        __syncthreads();
        if (tid == 0) {
            float best = -INFINITY; int bi = 0;
            for (int h = 0; h < HIS; ++h)
                if (pert[h] > best) { best = pert[h]; bi = h; }
            sel[bc * KK + i] = bi;
            lg[bi] = -INFINITY;
        }
        __syncthreads();
    }
}

// ---------------- Kernel F1: fusion MHSA -> mvf (all GEMMs MFMA) ----------------
__global__ __launch_bounds__(256) void kfus(
    const float* __restrict__ mv, const int* __restrict__ sel,
    const uint16_t* __restrict__ Wfrag, const uint16_t* __restrict__ WvF,
    float* __restrict__ mvf)
{
    __shared__ __align__(16) uint32_t xsb[64 * 256];   // 64 KB split x, SWZ
    __shared__ __align__(16) uint16_t qsb[64 * 256];   // 32 KB q bf16
    __shared__ __align__(16) float ps[64 * 65];        // 16.6 KB
    __shared__ __align__(16) float xv[64 * 16];        // 4 KB

    const int item = blockIdx.x;
    const int tid  = threadIdx.x;
    const int w    = tid >> 6, lane = tid & 63;
    const int g    = lane >> 4, ml = lane & 15;
    const int bc = item / KK, k = item - bc * KK;
    const int b  = bc / CDD;
    const int sh = sel[bc * KK + k];
    const float* cmv = mv + (size_t)bc * SS * EE;
    const float* hmv = mv + (size_t)(NCAND + b * HIS + sh) * SS * EE;
    float* out = mvf + (size_t)item * TT * EE;

    for (int p = tid; p < 64 * 64; p += 256) {
        int l = p >> 6, c = p & 63;
        float4 v = make_float4(0.f, 0.f, 0.f, 0.f);
        if (l < SS)                v = *(const float4*)&cmv[l * 256 + 4 * c];
        else if (l > SS && l < TT) v = *(const float4*)&hmv[(l - SS - 1) * 256 + 4 * c];
        uint4 s;
        s.x = splitpack(v.x); s.y = splitpack(v.y);
        s.z = splitpack(v.z); s.w = splitpack(v.w);
        *(uint4*)&xsb[SWZ(l, c)] = s;
    }
    __syncthreads();

    for (int h = 0; h < HH; ++h) {
        // ---- phase A: Q = X @ Wq_i[h], 3-term split MFMA -> qsb (bf16) ----
        {
            f32x4 acc[4][4];
            #pragma unroll
            for (int a = 0; a < 4; ++a)
                #pragma unroll
                for (int b2 = 0; b2 < 4; ++b2) acc[a][b2] = (f32x4){0.f, 0.f, 0.f, 0.f};
            const uint16_t* WH = Wfrag + (size_t)h * (8 * 16 * 64 * 16);
            for (int kt = 0; kt < 8; ++kt) {
                bf16x8 ah[4], al[4];
                #pragma unroll
                for (int mt = 0; mt < 4; ++mt) {
                    int row = mt * 16 + ml;
                    int c0 = kt * 8 + 2 * g;
                    uint4 A0 = *(const uint4*)&xsb[SWZ(row, c0)];
                    uint4 A1 = *(const uint4*)&xsb[SWZ(row, c0 + 1)];
                    ah[mt] = hi8(A0, A1);
                    al[mt] = lo8(A0, A1);
                }
                #pragma unroll
                for (int n2 = 0; n2 < 4; ++n2) {
                    const uint16_t* bp = WH + (((size_t)kt * 16 + (w * 4 + n2)) * 64 + lane) * 16;
                    bf16x8 bh = *(const bf16x8*)bp;
                    bf16x8 bl = *(const bf16x8*)(bp + 8);
                    #pragma unroll
                    for (int mt = 0; mt < 4; ++mt) {
                        acc[mt][n2] = MFMA16(ah[mt], bh, acc[mt][n2]);
                        acc[mt][n2] = MFMA16(al[mt], bh, acc[mt][n2]);
                        acc[mt][n2] = MFMA16(ah[mt], bl, acc[mt][n2]);
                    }
                }
            }
            // write q (bf16) -> qsb: pair even/odd cols via shfl_xor(1)
            #pragma unroll
            for (int mt = 0; mt < 4; ++mt)
                #pragma unroll
                for (int n2 = 0; n2 < 4; ++n2) {
                    #pragma unroll
                    for (int r = 0; r < 4; ++r) {
                        uint32_t mb = f2bf(acc[mt][n2][r]);
                        uint32_t ob = (uint32_t)__shfl_xor((int)mb, 1);
                        if ((ml & 1) == 0) {
                            int col0 = (w * 4 + n2) * 16 + ml;
                            int row = mt * 16 + g * 4 + r;
                            int idx = row * 256 + ((((col0 >> 3) ^ (row & 7)) << 3) | (col0 & 7));
                            *(uint32_t*)&qsb[idx] = mb | (ob << 16);
                        }
                    }
                }
        }
        __syncthreads();

        // ---- phase B: scores (1-term bf16 MFMA) + xv (1-term) + in-reg softmax ----
        {
            f32x4 accs[4];
            #pragma unroll
            for (int nt = 0; nt < 4; ++nt) accs[nt] = (f32x4){0.f, 0.f, 0.f, 0.f};
            f32x4 accv = (f32x4){0.f, 0.f, 0.f, 0.f};
            const int arow = 16 * w + ml;
            for (int kt = 0; kt < 8; ++kt) {
                int cq = 4 * kt + g;
                bf16x8 qh = *(const bf16x8*)&qsb[arow * 256 + ((cq ^ (arow & 7)) << 3)];
                int c0 = kt * 8 + 2 * g;
                #pragma unroll
                for (int nt = 0; nt < 4; ++nt) {
                    int brow = 16 * nt + ml;
                    uint4 X0 = *(const uint4*)&xsb[SWZ(brow, c0)];
                    uint4 X1 = *(const uint4*)&xsb[SWZ(brow, c0 + 1)];
                    accs[nt] = MFMA16(qh, hi8(X0, X1), accs[nt]);
                }
                // xv: A = x rows 16w.., B = WvF
                uint4 A0 = *(const uint4*)&xsb[SWZ(arow, c0)];
                uint4 A1 = *(const uint4*)&xsb[SWZ(arow, c0 + 1)];
                bf16x8 bh = *(const bf16x8*)&WvF[(((size_t)h * 8 + kt) * 64 + lane) * 16];
                accv = MFMA16(hi8(A0, A1), bh, accv);
            }
            // softmax rows l = 16w+4g+r over cols 0..60
            #pragma unroll
            for (int r = 0; r < 4; ++r) {
                float v0 = accs[0][r] * 0.0625f;
                float v1 = accs[1][r] * 0.0625f;
                float v2 = accs[2][r] * 0.0625f;
                float v3 = (ml < 13) ? accs[3][r] * 0.0625f : -INFINITY;  // cols 61..63 masked
                float mx = fmaxf(fmaxf(v0, v1), fmaxf(v2, v3));
                mx = fmaxf(mx, __shfl_xor(mx, 1));
                mx = fmaxf(mx, __shfl_xor(mx, 2));
                mx = fmaxf(mx, __shfl_xor(mx, 4));
                mx = fmaxf(mx, __shfl_xor(mx, 8));
                float e0 = expf(v0 - mx);
                float e1 = expf(v1 - mx);
                float e2 = expf(v2 - mx);
                float e3 = (ml < 13) ? expf(v3 - mx) : 0.f;
                float s = e0 + e1 + e2 + e3;
                s += __shfl_xor(s, 1); s += __shfl_xor(s, 2);
                s += __shfl_xor(s, 4); s += __shfl_xor(s, 8);
                float inv = 1.f / s;
                int lrow = 16 * w + 4 * g + r;
                if (lrow < TT) {
                    ps[lrow * 65 + ml]      = e0 * inv;
                    ps[lrow * 65 + 16 + ml] = e1 * inv;
                    ps[lrow * 65 + 32 + ml] = e2 * inv;
                    if (ml < 13) ps[lrow * 65 + 48 + ml] = e3 * inv;
                }
                int m = 16 * w + 4 * g + r;
                if (m < TT) xv[m * 16 + ml] = accv[r];
            }
        }
        __syncthreads();

        // ---- PV ----
        if (lane < TT) {
            const int l = lane, vq = w;
            float4 a = make_float4(0.f, 0.f, 0.f, 0.f);
            for (int m = 0; m < TT; ++m) {
                float pw = ps[l * 65 + m];
                float4 x4 = *(const float4*)&xv[m * 16 + vq * 4];
                a.x += pw * x4.x; a.y += pw * x4.y; a.z += pw * x4.z; a.w += pw * x4.w;
            }
            *(float4*)&out[l * 256 + h * 16 + vq * 4] = a;
        }
        // next phase A only writes qsb (safe: qsb readers passed the post-B barrier)
    }
}

// ---------------- Kernel F2: fusion pooling -> fvec ----------------
__global__ __launch_bounds__(256) void kpoolf(
    const float* __restrict__ mvf, const float* __restrict__ WkT,
    const float* __restrict__ bk, const float* __restrict__ qv,
    float* __restrict__ fvec)
{
    __shared__ float kq[TT * 201];
    __shared__ float scr[TT];
    __shared__ float wts[TT];
    const int item = blockIdx.x, tid = threadIdx.x;
    const float* src = mvf + (size_t)item * TT * EE;
    for (int p = tid; p < TT * 50; p += 256) {
        int l = p / 50, jq = p - l * 50;
        int j0 = jq * 4;
        float4 a = make_float4(bk[j0], bk[j0+1], bk[j0+2], bk[j0+3]);
        const float* mr = src + l * 256;
        for (int c = 0; c < 64; ++c) {
            float4 m4 = *(const float4*)&mr[4 * c];
            a.x += dot4(m4, *(const float4*)&WkT[(j0+0) * 256 + 4*c]);
            a.y += dot4(m4, *(const float4*)&WkT[(j0+1) * 256 + 4*c]);
            a.z += dot4(m4, *(const float4*)&WkT[(j0+2) * 256 + 4*c]);
            a.w += dot4(m4, *(const float4*)&WkT[(j0+3) * 256 + 4*c]);
        }
        kq[l*201 + j0 + 0] = tanhf(a.x) * qv[j0+0];
        kq[l*201 + j0 + 1] = tanhf(a.y) * qv[j0+1];
        kq[l*201 + j0 + 2] = tanhf(a.z) * qv[j0+2];
        kq[l*201 + j0 + 3] = tanhf(a.w) * qv[j0+3];
    }
    __syncthreads();
    if (tid < TT) {
        float a = 0.f;
        for (int j = 0; j < QD; ++j) a += kq[tid * 201 + j];
        scr[tid] = a * 0.0625f;
    }
    __syncthreads();
    if (tid == 0) {
        float mx = -INFINITY;
        for (int l = 0; l < TT; ++l) mx = fmaxf(mx, scr[l]);
        float sum = 0.f;
        for (int l = 0; l < TT; ++l) { float ev = expf(scr[l] - mx); wts[l] = ev; sum += ev; }
        float inv = 1.f / sum;
        for (int l = 0; l < TT; ++l) wts[l] *= inv;
    }
    __syncthreads();
    float a = 0.f;
    for (int l = 0; l < TT; ++l) a += wts[l] * src[l * 256 + tid];
    fvec[(size_t)item * EE + tid] = a;
}

// ---------------- Kernel Z: mean over K, score, log_softmax -> FP32 out ----------------
__global__ __launch_bounds__(256) void kfinal(
    const float* __restrict__ fvec, const float* __restrict__ Wl,
    const float* __restrict__ bl, float* __restrict__ out)
{
    const int b = blockIdx.x, tid = threadIdx.x;
    __shared__ float red[256];
    __shared__ float sc5[CDD];
    for (int c = 0; c < CDD; ++c) {
        size_t base = ((size_t)(b * CDD + c) * KK) * EE + tid;
        float f = (fvec[base] + fvec[base + EE] + fvec[base + 2 * EE]) * (1.f / 3.f);
        red[tid] = f * Wl[tid];
        __syncthreads();
        for (int s = 128; s > 0; s >>= 1) {
            if (tid < s) red[tid] += red[tid + s];
            __syncthreads();
        }
        if (tid == 0) sc5[c] = red[0] + bl[0];
        __syncthreads();
    }
    if (tid == 0) {
        float mx = -INFINITY;
        for (int c = 0; c < CDD; ++c) mx = fmaxf(mx, sc5[c]);
        float sum = 0.f;
        for (int c = 0; c < CDD; ++c) sum += expf(sc5[c] - mx);
        float lse = mx + logf(sum);
        for (int c = 0; c < CDD; ++c) out[b * CDD + c] = sc5[c] - lse;
    }
}

extern "C" void kernel_launch(void* const* d_in, const int* in_sizes, int n_in,
                              void* d_out, int out_size, void* d_ws, size_t ws_size,
                              hipStream_t stream) {
    const int*   cand = (const int*)d_in[0];
    const int*   clk  = (const int*)d_in[1];
    const float* emb  = (const float*)d_in[5];
    const float* Wq_w = (const float*)d_in[6];
    const float* Wv_w = (const float*)d_in[7];
    const float* Wk_w = (const float*)d_in[8];
    const float* bk_w = (const float*)d_in[9];
    const float* q_w  = (const float*)d_in[10];
    const float* Wq_i = (const float*)d_in[11];
    const float* Wv_i = (const float*)d_in[12];
    const float* Wk_i = (const float*)d_in[13];
    const float* bk_i = (const float*)d_in[14];
    const float* q_i  = (const float*)d_in[15];
    const float* Wl   = (const float*)d_in[16];
    const float* bl   = (const float*)d_in[17];

    // workspace layout (float units)
    float* ws     = (float*)d_ws;
    float* mv     = ws;                                   // 12,902,400
    float* repr   = mv   + (size_t)NITEM * SS * EE;       // 430,080
    float* mvf    = repr + (size_t)NITEM * EE;            // 3,747,840
    float* fvec   = mvf  + (size_t)NFUS * TT * EE;        // 61,440
    float* logits = fvec + (size_t)NFUS * EE;             // 8,000
    float* WkTw   = logits + NCAND * HIS;                 // 51,200
    float* WkTi   = WkTw + QD * EE;                       // 51,200
    int*   sel    = (int*)(WkTi + QD * EE);               // 256
    uint16_t* WfW = (uint16_t*)((float*)sel + 256);       // 2,097,152 u16
    uint16_t* WfI = WfW + (size_t)16 * 8 * 16 * 64 * 16;  // 2,097,152 u16
    uint16_t* WvFw = WfI + (size_t)16 * 8 * 16 * 64 * 16; // 131,072 u16
    uint16_t* WvFi = WvFw + (size_t)16 * 8 * 64 * 16;     // 131,072 u16

    ktrans<<<dim3(QD),    dim3(256), 0, stream>>>(Wk_w, WkTw);
    ktrans<<<dim3(QD),    dim3(256), 0, stream>>>(Wk_i, WkTi);
    kprep <<<dim3(128),   dim3(256), 0, stream>>>(Wq_w, WfW);
    kprep <<<dim3(128),   dim3(256), 0, stream>>>(Wq_i, WfI);
    kprepv<<<dim3(128),   dim3(64),  0, stream>>>(Wv_w, WvFw);
    kprepv<<<dim3(128),   dim3(64),  0, stream>>>(Wv_i, WvFi);
    kword <<<dim3(NITEM), dim3(256), 0, stream>>>(cand, clk, emb, WfW, WvFw, WkTw, bk_w, q_w, mv, repr);
    klogit<<<dim3(NCAND), dim3(128), 0, stream>>>(repr, logits);
    ksel  <<<dim3(NCAND), dim3(128), 0, stream>>>(logits, sel);
    kfus  <<<dim3(NFUS),  dim3(256), 0, stream>>>(mv, sel, WfI, WvFi, mvf);
    kpoolf<<<dim3(NFUS),  dim3(256), 0, stream>>>(mvf, WkTi, bk_i, q_i, fvec);
    kfinal<<<dim3(BB),    dim3(256), 0, stream>>>(fvec, Wl, bl, (float*)d_out);
}